// Round 8
// baseline (82.298 us; speedup 1.0000x reference)
//
#include <hip/hip_runtime.h>

#define B_   4
#define C_   64
#define H_   128
#define W_   128
#define KS   7
#define G_   4
#define GC_  16
#define KK   49
#define PAD  3
#define TH   8
#define TW   16
#define HW_  (H_ * W_)
#define NPX  (TH * TW)         // 128 px per block
#define ZROWB 288              // bytes per z k-row: 128 px * 2B + 32B pad (16B aligned)

typedef float f32x4  __attribute__((ext_vector_type(4)));
typedef short bf16x8 __attribute__((ext_vector_type(8)));
typedef unsigned int u32x4 __attribute__((ext_vector_type(4)));
typedef unsigned int u32x2 __attribute__((ext_vector_type(2)));

__device__ __forceinline__ unsigned f2bf(float f) {   // RNE float->bf16 (low 16)
    unsigned u = __float_as_uint(f);
    unsigned r = u + 0x7FFFu + ((u >> 16) & 1u);
    return r >> 16;
}

#define BFLO(u) __uint_as_float((u) << 16)
#define BFHI(u) __uint_as_float((u) & 0xFFFF0000u)

__global__ __launch_bounds__(256, 8) void invol_mfma6(
    const float* __restrict__ x,
    const float* __restrict__ cw,
    const float* __restrict__ bng,
    const float* __restrict__ bnb,
    const float* __restrict__ bnm,
    const float* __restrict__ bnv,
    float* __restrict__ out)
{
    __shared__ __align__(16) unsigned short z_sh[KK * (ZROWB / 2)]; // 14112 B
    __shared__ float sscale[KK], sbias[KK];

    const int tid  = threadIdx.x;
    const int lane = tid & 63;
    const int wv   = tid >> 6;        // wave 0..3
    const int l15  = lane & 15;
    const int l4   = lane >> 4;

    const int bx = blockIdx.x;
    const int w0 = bx * TW;
    const int h0 = blockIdx.y * TH;
    const int bz = blockIdx.z;        // b*G + g
    const int b  = bz >> 2;
    const int g  = bz & 3;

    // ---- BN constants ----
    if (tid < KK) {
        const int o = g * KK + tid;
        const float s = bng[o] * rsqrtf(bnv[o] + 1e-5f);
        sscale[tid] = s;
        sbias[tid]  = bnb[o] - bnm[o] * s;
    }

    // ---- A fragments: A[px][c], px = (wv*2+mt)*16 + l15  (y = mtg, x = l15) ----
    bf16x8 afr[2][2];
    {
        const float* xb = x + (size_t)b * C_ * HW_;
#pragma unroll
        for (int mt = 0; mt < 2; ++mt) {
            const int hh = h0 + wv * 2 + mt;
            const float* xp = xb + hh * W_ + (w0 + l15);
#pragma unroll
            for (int ks = 0; ks < 2; ++ks) {
                const int c0 = ks * 32 + l4 * 8;
                bf16x8 a;
#pragma unroll
                for (int j = 0; j < 8; ++j)
                    a[j] = (short)f2bf(xp[(size_t)(c0 + j) * HW_]);
                afr[mt][ks] = a;
            }
        }
    }

    // ---- B fragments: B[c][k], k = nt*16 + l15 (zero-padded past 49) ----
    bf16x8 bfr[4][2];
    {
#pragma unroll
        for (int nt = 0; nt < 4; ++nt) {
            const int kout = nt * 16 + l15;
            const bool kv = (kout < KK);
            const float* wp = cw + (size_t)(g * KK + (kv ? kout : 0)) * C_;
#pragma unroll
            for (int ks = 0; ks < 2; ++ks) {
                const int c0 = ks * 32 + l4 * 8;
                bf16x8 bb;
#pragma unroll
                for (int j = 0; j < 8; ++j)
                    bb[j] = kv ? (short)f2bf(wp[c0 + j]) : (short)0;
                bfr[nt][ks] = bb;
            }
        }
    }

    __syncthreads();   // sscale/sbias visible

    // ---- MFMA: z[px][k], M=128 N=64(49) K=64 ----
    f32x4 acc1[2][4];
#pragma unroll
    for (int mt = 0; mt < 2; ++mt)
#pragma unroll
        for (int nt = 0; nt < 4; ++nt) {
            f32x4 a = {0.f, 0.f, 0.f, 0.f};
            a = __builtin_amdgcn_mfma_f32_16x16x32_bf16(afr[mt][0], bfr[nt][0], a, 0, 0, 0);
            a = __builtin_amdgcn_mfma_f32_16x16x32_bf16(afr[mt][1], bfr[nt][1], a, 0, 0, 0);
            acc1[mt][nt] = a;
        }

    // ---- epilogue: BN+SiLU, packed b64 writes into z[k][px] ----
#pragma unroll
    for (int nt = 0; nt < 4; ++nt) {
        const int k = nt * 16 + l15;
        if (k < KK) {
            const float sc = sscale[k];
            const float bi = sbias[k];
#pragma unroll
            for (int mt = 0; mt < 2; ++mt) {
                const int px0 = (wv * 2 + mt) * 16 + l4 * 4;
                const float t0 = acc1[mt][nt][0] * sc + bi;
                const float t1 = acc1[mt][nt][1] * sc + bi;
                const float t2 = acc1[mt][nt][2] * sc + bi;
                const float t3 = acc1[mt][nt][3] * sc + bi;
                const float v0 = __fdividef(t0, 1.0f + __expf(-t0));
                const float v1 = __fdividef(t1, 1.0f + __expf(-t1));
                const float v2 = __fdividef(t2, 1.0f + __expf(-t2));
                const float v3 = __fdividef(t3, 1.0f + __expf(-t3));
                u32x2 wpk;
                wpk[0] = f2bf(v0) | (f2bf(v1) << 16);
                wpk[1] = f2bf(v2) | (f2bf(v3) << 16);
                *(u32x2*)((char*)z_sh + k * ZROWB + px0 * 2) = wpk;
            }
        }
    }

    __syncthreads();   // z visible

    // ---- involution: thread = (c2, y8, xh) owns 8 outputs ----
    const int c2 = tid >> 4;          // 0..15
    const int y8 = (tid >> 1) & 7;    // 0..7
    const int xh = tid & 1;           // 0..1
    const bool ledge = (bx == 0) & (xh == 0);
    const bool redge = (bx == W_ / TW - 1) & (xh == 1);

    float a0 = 0.f, a1 = 0.f, a2 = 0.f, a3 = 0.f;
    float a4 = 0.f, a5 = 0.f, a6 = 0.f, a7 = 0.f;

    const float* xc = x + (size_t)(b * C_ + g * GC_ + c2) * HW_;
    const char* zby = (const char*)z_sh + y8 * 32 + xh * 16;   // + k*ZROWB

#pragma unroll 1
    for (int kh = 0; kh < KS; ++kh) {
        const int gh = h0 + y8 + kh - PAD;
        const bool rowok = (gh >= 0) & (gh < H_);
        const int ghc = gh < 0 ? 0 : (gh > H_ - 1 ? H_ - 1 : gh);
        const float* rp = xc + (size_t)ghc * W_;

        // row[j] = x[.., w0 + xh*8 + j - 3], j in [0,14)
        float f0, f1, f2, f3, f4, f5, f6, f7, f8, f9, f10, f11, f12, f13;
        if (ledge) {
            const f32x4* vp = (const f32x4*)rp;               // x = 0..11
            const f32x4 q0 = vp[0], q1 = vp[1], q2 = vp[2];
            f0 = 0.f; f1 = 0.f; f2 = 0.f;
            f3 = q0[0]; f4 = q0[1]; f5 = q0[2]; f6 = q0[3];
            f7 = q1[0]; f8 = q1[1]; f9 = q1[2]; f10 = q1[3];
            f11 = q2[0]; f12 = q2[1]; f13 = q2[2];
        } else if (redge) {
            const f32x4* vp = (const f32x4*)(rp + 116);       // x = 116..127
            const f32x4 q0 = vp[0], q1 = vp[1], q2 = vp[2];
            f0 = q0[1]; f1 = q0[2]; f2 = q0[3];
            f3 = q1[0]; f4 = q1[1]; f5 = q1[2]; f6 = q1[3];
            f7 = q2[0]; f8 = q2[1]; f9 = q2[2]; f10 = q2[3];
            f11 = 0.f; f12 = 0.f; f13 = 0.f;
        } else {
            const f32x4* vp = (const f32x4*)(rp + w0 + xh * 8 - 4);
            const f32x4 q0 = vp[0], q1 = vp[1], q2 = vp[2], q3 = vp[3];
            f0 = q0[1]; f1 = q0[2]; f2 = q0[3];
            f3 = q1[0]; f4 = q1[1]; f5 = q1[2]; f6 = q1[3];
            f7 = q2[0]; f8 = q2[1]; f9 = q2[2]; f10 = q2[3];
            f11 = q3[0]; f12 = q3[1]; f13 = q3[2];
        }
        float row[14] = { f0, f1, f2, f3, f4, f5, f6, f7, f8, f9, f10, f11, f12, f13 };

        if (rowok) {   // exec-mask predication
            const char* zrow = zby + kh * (KS * ZROWB);
#pragma unroll
            for (int kw = 0; kw < KS; ++kw) {
                const u32x4 q = *(const u32x4*)(zrow + kw * ZROWB);  // 8 px
                a0 = fmaf(BFLO(q[0]), row[kw + 0], a0);
                a1 = fmaf(BFHI(q[0]), row[kw + 1], a1);
                a2 = fmaf(BFLO(q[1]), row[kw + 2], a2);
                a3 = fmaf(BFHI(q[1]), row[kw + 3], a3);
                a4 = fmaf(BFLO(q[2]), row[kw + 4], a4);
                a5 = fmaf(BFHI(q[2]), row[kw + 5], a5);
                a6 = fmaf(BFLO(q[3]), row[kw + 6], a6);
                a7 = fmaf(BFHI(q[3]), row[kw + 7], a7);
            }
        }
    }

    // ---- coalesced stores: 2x float4 ----
    float* og = out + (size_t)(b * C_ + g * GC_ + c2) * HW_
                    + (h0 + y8) * W_ + w0 + xh * 8;
    {
        f32x4 v;
        v[0] = a0; v[1] = a1; v[2] = a2; v[3] = a3;
        *(f32x4*)(og + 0) = v;
        v[0] = a4; v[1] = a5; v[2] = a6; v[3] = a7;
        *(f32x4*)(og + 4) = v;
    }
}

extern "C" void kernel_launch(void* const* d_in, const int* in_sizes, int n_in,
                              void* d_out, int out_size, void* d_ws, size_t ws_size,
                              hipStream_t stream) {
    const float* x   = (const float*)d_in[0];
    const float* cw  = (const float*)d_in[1];
    const float* bng = (const float*)d_in[2];
    const float* bnb = (const float*)d_in[3];
    const float* bnm = (const float*)d_in[4];
    const float* bnv = (const float*)d_in[5];
    float* out = (float*)d_out;

    dim3 grid(W_ / TW, H_ / TH, B_ * G_);   // 8 x 16 x 16 = 2048 blocks
    dim3 block(256);
    invol_mfma6<<<grid, block, 0, stream>>>(x, cw, bng, bnb, bnm, bnv, out);
}

// Round 10
// 51.474 us; speedup vs baseline: 1.5988x; 1.5988x over previous
//
#include <hip/hip_runtime.h>

#define B_   4
#define C_   64
#define H_   128
#define W_   128
#define KS   7
#define G_   4
#define GC_  16
#define KK   49
#define PAD  3
#define TH   8
#define TW   16
#define HW_  (H_ * W_)
#define NPX  (TH * TW)         // 128 px per block
#define ZROWB 288              // bytes per z k-row: 128 px * 2B + 32B pad (16B aligned)

typedef float f32x4  __attribute__((ext_vector_type(4)));
typedef short bf16x8 __attribute__((ext_vector_type(8)));
typedef unsigned int u32x4 __attribute__((ext_vector_type(4)));
typedef unsigned int u32x2 __attribute__((ext_vector_type(2)));

__device__ __forceinline__ unsigned f2bf(float f) {   // RNE float->bf16 (low 16)
    unsigned u = __float_as_uint(f);
    unsigned r = u + 0x7FFFu + ((u >> 16) & 1u);
    return r >> 16;
}

#define BFLO(u) __uint_as_float((u) << 16)
#define BFHI(u) __uint_as_float((u) & 0xFFFF0000u)

// (256,8) forced VGPR=32 -> spill (r8). (256,6) produced NaN (r9, unexplained
// -- flake or cap-specific miscompile; not resubmitted). (256,4) = 128-VGPR
// cap, known-good config class (r6); natural demand ~64-90 VGPR, no spill.
__global__ __launch_bounds__(256, 4) void invol_mfma8(
    const float* __restrict__ x,
    const float* __restrict__ cw,
    const float* __restrict__ bng,
    const float* __restrict__ bnb,
    const float* __restrict__ bnm,
    const float* __restrict__ bnv,
    float* __restrict__ out)
{
    __shared__ __align__(16) unsigned short z_sh[KK * (ZROWB / 2)]; // 14112 B
    __shared__ float sscale[KK], sbias[KK];

    const int tid  = threadIdx.x;
    const int lane = tid & 63;
    const int wv   = tid >> 6;        // wave 0..3
    const int l15  = lane & 15;
    const int l4   = lane >> 4;

    const int bx = blockIdx.x;
    const int w0 = bx * TW;
    const int h0 = blockIdx.y * TH;
    const int bz = blockIdx.z;        // b*G + g
    const int b  = bz >> 2;
    const int g  = bz & 3;

    // ---- BN constants ----
    if (tid < KK) {
        const int o = g * KK + tid;
        const float s = bng[o] * rsqrtf(bnv[o] + 1e-5f);
        sscale[tid] = s;
        sbias[tid]  = bnb[o] - bnm[o] * s;
    }

    // ---- A fragments: A[px][c], px = (wv*2+mt)*16 + l15  (y = mtg, x = l15) ----
    bf16x8 afr[2][2];
    {
        const float* xb = x + (size_t)b * C_ * HW_;
#pragma unroll
        for (int mt = 0; mt < 2; ++mt) {
            const int hh = h0 + wv * 2 + mt;
            const float* xp = xb + hh * W_ + (w0 + l15);
#pragma unroll
            for (int ks = 0; ks < 2; ++ks) {
                const int c0 = ks * 32 + l4 * 8;
                bf16x8 a;
#pragma unroll
                for (int j = 0; j < 8; ++j)
                    a[j] = (short)f2bf(xp[(size_t)(c0 + j) * HW_]);
                afr[mt][ks] = a;
            }
        }
    }

    // ---- B fragments: B[c][k], k = nt*16 + l15 (zero-padded past 49) ----
    bf16x8 bfr[4][2];
    {
#pragma unroll
        for (int nt = 0; nt < 4; ++nt) {
            const int kout = nt * 16 + l15;
            const bool kv = (kout < KK);
            const float* wp = cw + (size_t)(g * KK + (kv ? kout : 0)) * C_;
#pragma unroll
            for (int ks = 0; ks < 2; ++ks) {
                const int c0 = ks * 32 + l4 * 8;
                bf16x8 bb;
#pragma unroll
                for (int j = 0; j < 8; ++j)
                    bb[j] = kv ? (short)f2bf(wp[c0 + j]) : (short)0;
                bfr[nt][ks] = bb;
            }
        }
    }

    __syncthreads();   // sscale/sbias visible

    // ---- MFMA: z[px][k], M=128 N=64(49) K=64 ----
    f32x4 acc1[2][4];
#pragma unroll
    for (int mt = 0; mt < 2; ++mt)
#pragma unroll
        for (int nt = 0; nt < 4; ++nt) {
            f32x4 a = {0.f, 0.f, 0.f, 0.f};
            a = __builtin_amdgcn_mfma_f32_16x16x32_bf16(afr[mt][0], bfr[nt][0], a, 0, 0, 0);
            a = __builtin_amdgcn_mfma_f32_16x16x32_bf16(afr[mt][1], bfr[nt][1], a, 0, 0, 0);
            acc1[mt][nt] = a;
        }

    // ---- epilogue: BN+SiLU, packed b64 writes into z[k][px] ----
#pragma unroll
    for (int nt = 0; nt < 4; ++nt) {
        const int k = nt * 16 + l15;
        if (k < KK) {
            const float sc = sscale[k];
            const float bi = sbias[k];
#pragma unroll
            for (int mt = 0; mt < 2; ++mt) {
                const int px0 = (wv * 2 + mt) * 16 + l4 * 4;
                const float t0 = acc1[mt][nt][0] * sc + bi;
                const float t1 = acc1[mt][nt][1] * sc + bi;
                const float t2 = acc1[mt][nt][2] * sc + bi;
                const float t3 = acc1[mt][nt][3] * sc + bi;
                const float v0 = __fdividef(t0, 1.0f + __expf(-t0));
                const float v1 = __fdividef(t1, 1.0f + __expf(-t1));
                const float v2 = __fdividef(t2, 1.0f + __expf(-t2));
                const float v3 = __fdividef(t3, 1.0f + __expf(-t3));
                u32x2 wpk;
                wpk[0] = f2bf(v0) | (f2bf(v1) << 16);
                wpk[1] = f2bf(v2) | (f2bf(v3) << 16);
                *(u32x2*)((char*)z_sh + k * ZROWB + px0 * 2) = wpk;
            }
        }
    }

    __syncthreads();   // z visible

    // ---- involution: thread = (c2, y8, xh) owns 8 outputs ----
    const int c2 = tid >> 4;          // 0..15
    const int y8 = (tid >> 1) & 7;    // 0..7
    const int xh = tid & 1;           // 0..1
    const bool ledge = (bx == 0) & (xh == 0);
    const bool redge = (bx == W_ / TW - 1) & (xh == 1);

    float a0 = 0.f, a1 = 0.f, a2 = 0.f, a3 = 0.f;
    float a4 = 0.f, a5 = 0.f, a6 = 0.f, a7 = 0.f;

    const float* xc = x + (size_t)(b * C_ + g * GC_ + c2) * HW_;
    const char* zby = (const char*)z_sh + y8 * 32 + xh * 16;   // + k*ZROWB

#pragma unroll 1
    for (int kh = 0; kh < KS; ++kh) {
        const int gh = h0 + y8 + kh - PAD;
        const bool rowok = (gh >= 0) & (gh < H_);
        const int ghc = gh < 0 ? 0 : (gh > H_ - 1 ? H_ - 1 : gh);
        const float* rp = xc + (size_t)ghc * W_;

        // row[j] = x[.., w0 + xh*8 + j - 3], j in [0,14)
        float f0, f1, f2, f3, f4, f5, f6, f7, f8, f9, f10, f11, f12, f13;
        if (ledge) {
            const f32x4* vp = (const f32x4*)rp;               // x = 0..11
            const f32x4 q0 = vp[0], q1 = vp[1], q2 = vp[2];
            f0 = 0.f; f1 = 0.f; f2 = 0.f;
            f3 = q0[0]; f4 = q0[1]; f5 = q0[2]; f6 = q0[3];
            f7 = q1[0]; f8 = q1[1]; f9 = q1[2]; f10 = q1[3];
            f11 = q2[0]; f12 = q2[1]; f13 = q2[2];
        } else if (redge) {
            const f32x4* vp = (const f32x4*)(rp + 116);       // x = 116..127
            const f32x4 q0 = vp[0], q1 = vp[1], q2 = vp[2];
            f0 = q0[1]; f1 = q0[2]; f2 = q0[3];
            f3 = q1[0]; f4 = q1[1]; f5 = q1[2]; f6 = q1[3];
            f7 = q2[0]; f8 = q2[1]; f9 = q2[2]; f10 = q2[3];
            f11 = 0.f; f12 = 0.f; f13 = 0.f;
        } else {
            const f32x4* vp = (const f32x4*)(rp + w0 + xh * 8 - 4);
            const f32x4 q0 = vp[0], q1 = vp[1], q2 = vp[2], q3 = vp[3];
            f0 = q0[1]; f1 = q0[2]; f2 = q0[3];
            f3 = q1[0]; f4 = q1[1]; f5 = q1[2]; f6 = q1[3];
            f7 = q2[0]; f8 = q2[1]; f9 = q2[2]; f10 = q2[3];
            f11 = q3[0]; f12 = q3[1]; f13 = q3[2];
        }
        float row[14] = { f0, f1, f2, f3, f4, f5, f6, f7, f8, f9, f10, f11, f12, f13 };

        if (rowok) {   // exec-mask predication
            const char* zrow = zby + kh * (KS * ZROWB);
#pragma unroll
            for (int kw = 0; kw < KS; ++kw) {
                const u32x4 q = *(const u32x4*)(zrow + kw * ZROWB);  // 8 px
                a0 = fmaf(BFLO(q[0]), row[kw + 0], a0);
                a1 = fmaf(BFHI(q[0]), row[kw + 1], a1);
                a2 = fmaf(BFLO(q[1]), row[kw + 2], a2);
                a3 = fmaf(BFHI(q[1]), row[kw + 3], a3);
                a4 = fmaf(BFLO(q[2]), row[kw + 4], a4);
                a5 = fmaf(BFHI(q[2]), row[kw + 5], a5);
                a6 = fmaf(BFLO(q[3]), row[kw + 6], a6);
                a7 = fmaf(BFHI(q[3]), row[kw + 7], a7);
            }
        }
    }

    // ---- coalesced stores: 2x float4 ----
    float* og = out + (size_t)(b * C_ + g * GC_ + c2) * HW_
                    + (h0 + y8) * W_ + w0 + xh * 8;
    {
        f32x4 v;
        v[0] = a0; v[1] = a1; v[2] = a2; v[3] = a3;
        *(f32x4*)(og + 0) = v;
        v[0] = a4; v[1] = a5; v[2] = a6; v[3] = a7;
        *(f32x4*)(og + 4) = v;
    }
}

extern "C" void kernel_launch(void* const* d_in, const int* in_sizes, int n_in,
                              void* d_out, int out_size, void* d_ws, size_t ws_size,
                              hipStream_t stream) {
    const float* x   = (const float*)d_in[0];
    const float* cw  = (const float*)d_in[1];
    const float* bng = (const float*)d_in[2];
    const float* bnb = (const float*)d_in[3];
    const float* bnm = (const float*)d_in[4];
    const float* bnv = (const float*)d_in[5];
    float* out = (float*)d_out;

    dim3 grid(W_ / TW, H_ / TH, B_ * G_);   // 8 x 16 x 16 = 2048 blocks
    dim3 block(256);
    invol_mfma8<<<grid, block, 0, stream>>>(x, cw, bng, bnb, bnm, bnv, out);
}